// Round 6
// baseline (480.806 us; speedup 1.0000x reference)
//
#include <hip/hip_runtime.h>

#define NN 100000
#define NE 1600000
#define DD 128
#define BM 64
#define NPB 256                   // nodes per bucket
#define NBUCK 391                 // ceil(NN / NPB)
#define ECHUNK 8192
#define NBLK_PART 196             // ceil(NE / ECHUNK)
#define CAP 8192                  // LDS staging capacity (mean bucket = 4096 edges)
#define CVW_BLK 384
#define SLICE_SHORTS ((size_t)NN * 16)   // one 16-dim slice, 3.2 MB
#define AGG_TILE 1024
#define AGG_GRID ((98) * 8)       // 98 tiles of 1024 nodes x 8 slices

typedef __attribute__((ext_vector_type(2))) float f32x2;
typedef __attribute__((ext_vector_type(4))) float f32x4;
typedef __attribute__((ext_vector_type(8))) short bf16x8;

__device__ inline unsigned short f2bf(float f) {
    unsigned int x = __builtin_bit_cast(unsigned int, f);
    unsigned int r = x + 0x7fffu + ((x >> 16) & 1u);
    return (unsigned short)(r >> 16);
}
__device__ inline float bf_lo(unsigned int u) { return __builtin_bit_cast(float, u << 16); }
__device__ inline float bf_hi(unsigned int u) { return __builtin_bit_cast(float, u & 0xffff0000u); }
__device__ inline unsigned int packbf(float a, float b) {
    return (unsigned int)f2bf(a) | ((unsigned int)f2bf(b) << 16);
}

__device__ inline void load_g2l_16(const void* gsrc, void* ldst) {
    __builtin_amdgcn_global_load_lds(
        (const __attribute__((address_space(1))) void*)(uintptr_t)gsrc,
        (__attribute__((address_space(3))) void*)(uintptr_t)ldst,
        16, 0, 0);
}

// ---------------- prep: weights transpose + bucket hist ----------------

__global__ __launch_bounds__(256) void prep_wh(
    const float* __restrict__ w0, const float* __restrict__ w1,
    const float* __restrict__ w2, const float* __restrict__ w3,
    const float* __restrict__ w4, const float* __restrict__ w5,
    unsigned short* __restrict__ wtall,
    const int* __restrict__ row, int* __restrict__ gcnt) {
    __shared__ int cnt[NBUCK];
    const int b = blockIdx.x;
    if (b < CVW_BLK) {
        int t = b * 256 + threadIdx.x;   // 0 .. 6*16384-1
        int i = t >> 14;
        int r = t & 16383;
        const float* W = (i == 0) ? w0 : (i == 1) ? w1 : (i == 2) ? w2
                        : (i == 3) ? w3 : (i == 4) ? w4 : w5;
        int c = r >> 7, k = r & 127;
        wtall[t] = f2bf(W[k * DD + c]);
    } else {
        for (int i = threadIdx.x; i < NBUCK; i += 256) cnt[i] = 0;
        __syncthreads();
        int base = (b - CVW_BLK) * ECHUNK;
        int end = base + ECHUNK; if (end > NE) end = NE;
        for (int i = base + threadIdx.x; i < end; i += 256)
            atomicAdd(&cnt[row[i] >> 8], 1);
        __syncthreads();
        for (int i = threadIdx.x; i < NBUCK; i += 256) {
            int c = cnt[i];
            if (c) atomicAdd(&gcnt[i], c);
        }
    }
}

// x (fp32 row-major) -> xs (bf16 slice-major): xs[f][n][16]
__global__ __launch_bounds__(256) void conv_x_sliced(const float* __restrict__ x,
                                                     unsigned short* __restrict__ xs) {
    __shared__ unsigned short tile[BM * DD];   // 16KB
    const int row0 = blockIdx.x * BM;
    const int tid = threadIdx.x;
    char* ldsB = (char*)tile;
#pragma unroll
    for (int it = 0; it < 8; ++it) {
        int idx = it * 256 + tid;           // 2048 float4 units
        int r = idx >> 5, q4 = idx & 31;
        if (row0 + r < NN) {
            float4 v = *reinterpret_cast<const float4*>(&x[(size_t)(row0 + r) * DD + q4 * 4]);
            uint2 pk;
            pk.x = packbf(v.x, v.y);
            pk.y = packbf(v.z, v.w);
            *reinterpret_cast<uint2*>(ldsB + r * 256 + q4 * 8) = pk;
        }
    }
    __syncthreads();
#pragma unroll
    for (int it = 0; it < 4; ++it) {
        int u = it * 256 + tid;             // 1024 units: 8f x 64r x 2half
        int f = u >> 7, rem = u & 127;
        int r = rem >> 1, half = rem & 1;
        int n = row0 + r;
        if (n < NN) {
            uint4 v = *reinterpret_cast<const uint4*>(ldsB + r * 256 + f * 32 + half * 16);
            *reinterpret_cast<uint4*>(xs + (size_t)f * SLICE_SHORTS + (size_t)n * 16 + half * 8) = v;
        }
    }
}

// ---------------- bucketed CSR build ----------------

__global__ __launch_bounds__(512) void bucket_scan(const int* __restrict__ gcnt,
                                                   int* __restrict__ gbase) {
    __shared__ int sm[512];
    int t = threadIdx.x;
    sm[t] = (t < NBUCK) ? gcnt[t] : 0;
    __syncthreads();
    for (int off = 1; off < 512; off <<= 1) {
        int add = (t >= off) ? sm[t - off] : 0;
        __syncthreads();
        sm[t] += add;
        __syncthreads();
    }
    if (t < NBUCK) gbase[t + 1] = sm[t];
    if (t == 0) gbase[0] = 0;
}

__global__ __launch_bounds__(256) void bucket_scatter(const int* __restrict__ row,
                                                      const int* __restrict__ col,
                                                      const int* __restrict__ gbase,
                                                      int* __restrict__ gcursor,
                                                      uint2* __restrict__ ebuf) {
    __shared__ int cnt[NBUCK];
    __shared__ int base[NBUCK];
    for (int i = threadIdx.x; i < NBUCK; i += 256) cnt[i] = 0;
    __syncthreads();
    int cbase = blockIdx.x * ECHUNK;
    int cend = cbase + ECHUNK; if (cend > NE) cend = NE;
    for (int i = cbase + threadIdx.x; i < cend; i += 256)
        atomicAdd(&cnt[row[i] >> 8], 1);
    __syncthreads();
    for (int i = threadIdx.x; i < NBUCK; i += 256) {
        int c = cnt[i];
        cnt[i] = 0;
        base[i] = c ? (gbase[i] + atomicAdd(&gcursor[i], c)) : 0;
    }
    __syncthreads();
    for (int i = cbase + threadIdx.x; i < cend; i += 256) {
        int r = row[i], c = col[i];
        int b = r >> 8;
        int k = atomicAdd(&cnt[b], 1);
        ebuf[base[b] + k] = uint2{(unsigned)r, (unsigned)c};
    }
}

__global__ __launch_bounds__(256) void csr_build(const uint2* __restrict__ ebuf,
                                                 const int* __restrict__ gbase,
                                                 int* __restrict__ offs,
                                                 int* __restrict__ csr_col) {
    __shared__ int dcnt[NPB];
    __shared__ int doff[NPB];
    __shared__ int sm[NPB];
    __shared__ int stage[CAP];
    const int b = blockIdx.x;
    const int es = gbase[b], ee = gbase[b + 1];
    const int m = ee - es;
    const int t = threadIdx.x;
    const int nbase = b * NPB;

    dcnt[t] = 0;
    __syncthreads();
    for (int i = es + t; i < ee; i += 256) {
        int ln = (int)ebuf[i].x - nbase;
        atomicAdd(&dcnt[ln], 1);
    }
    __syncthreads();
    sm[t] = dcnt[t];
    __syncthreads();
    for (int off = 1; off < 256; off <<= 1) {
        int add = (t >= off) ? sm[t - off] : 0;
        __syncthreads();
        sm[t] += add;
        __syncthreads();
    }
    doff[t] = sm[t] - dcnt[t];
    int node = nbase + t;
    if (node < NN) offs[node + 1] = es + sm[t];
    if (b == 0 && t == 0) offs[0] = 0;
    dcnt[t] = 0;
    __syncthreads();

    if (m <= CAP) {
        for (int i = es + t; i < ee; i += 256) {
            uint2 e = ebuf[i];
            int ln = (int)e.x - nbase;
            int k = atomicAdd(&dcnt[ln], 1);
            stage[doff[ln] + k] = (int)e.y;
        }
        __syncthreads();
        for (int i = t; i < m; i += 256) csr_col[es + i] = stage[i];
    } else {
        for (int i = es + t; i < ee; i += 256) {
            uint2 e = ebuf[i];
            int ln = (int)e.x - nbase;
            int k = atomicAdd(&dcnt[ln], 1);
            csr_col[es + doff[ln] + k] = (int)e.y;
        }
    }
}

// ---------------- sliced mean-aggregation (XCD-pinned) ----------------

// block = (tile = bid>>3, slice f = bid&7); XCD bid%8 only touches slice f
// (3.2 MB, fits 4 MB per-XCD L2). 512 threads = 256 pairs; pair = one node's
// 16-dim slice (lane half: 8 dims = 16B). Row work-stealing via LDS counter.
__global__ __launch_bounds__(512) void agg_sliced(const unsigned short* __restrict__ hs,
                                                  const int* __restrict__ offs,
                                                  const int* __restrict__ csr_col,
                                                  unsigned short* __restrict__ aggs) {
    __shared__ int nextrow;
    if (threadIdx.x == 0) nextrow = 0;
    __syncthreads();
    const int f = blockIdx.x & 7;
    const int node0 = (blockIdx.x >> 3) * AGG_TILE;
    const int lane = threadIdx.x & 63;
    const int half = threadIdx.x & 1;
    const unsigned short* hsf = hs + (size_t)f * SLICE_SHORTS + half * 8;
    unsigned short* aggf = aggs + (size_t)f * SLICE_SHORTS + half * 8;

    while (true) {
        int r = 0;
        if (!(lane & 1)) r = atomicAdd(&nextrow, 1);
        r = __shfl(r, lane & ~1, 64);
        if (r >= AGG_TILE) break;
        int n = node0 + r;
        if (n >= NN) continue;
        int s = offs[n], e = offs[n + 1];
        f32x2 a0 = {0.f, 0.f}, a1 = {0.f, 0.f}, a2 = {0.f, 0.f}, a3 = {0.f, 0.f};
        int p = s;
        for (; p + 8 <= e; p += 8) {
            uint4 v[8];
#pragma unroll
            for (int q = 0; q < 8; ++q) {
                int c = csr_col[p + q];
                v[q] = *reinterpret_cast<const uint4*>(hsf + (size_t)c * 16);
            }
#pragma unroll
            for (int q = 0; q < 8; ++q) {
                a0 += (f32x2){bf_lo(v[q].x), bf_hi(v[q].x)};
                a1 += (f32x2){bf_lo(v[q].y), bf_hi(v[q].y)};
                a2 += (f32x2){bf_lo(v[q].z), bf_hi(v[q].z)};
                a3 += (f32x2){bf_lo(v[q].w), bf_hi(v[q].w)};
            }
        }
        for (; p < e; ++p) {
            int c = csr_col[p];
            uint4 v = *reinterpret_cast<const uint4*>(hsf + (size_t)c * 16);
            a0 += (f32x2){bf_lo(v.x), bf_hi(v.x)};
            a1 += (f32x2){bf_lo(v.y), bf_hi(v.y)};
            a2 += (f32x2){bf_lo(v.z), bf_hi(v.z)};
            a3 += (f32x2){bf_lo(v.w), bf_hi(v.w)};
        }
        float inv = (e > s) ? (1.0f / (float)(e - s)) : 0.0f;
        uint4 o;
        o.x = packbf(a0[0] * inv, a0[1] * inv);
        o.y = packbf(a1[0] * inv, a1[1] * inv);
        o.z = packbf(a2[0] * inv, a2[1] * inv);
        o.w = packbf(a3[0] * inv, a3[1] * inv);
        *reinterpret_cast<uint4*>(aggf + (size_t)n * 16) = o;
    }
}

// ---------------- GEMM: relu(A@Wl + H@Wr + b) from sliced A,H ----------------

__global__ __launch_bounds__(256) void gemm_sliced(
    const unsigned short* __restrict__ aggs, const unsigned short* __restrict__ hs,
    const unsigned short* __restrict__ WlT, const unsigned short* __restrict__ WrT,
    const float* __restrict__ bias, float* __restrict__ out,
    unsigned short* __restrict__ hbn) {
    __shared__ uint4 smem4[2048];            // 32KB: A(16KB) + H(16KB); reused fp32 out tile
    char* ldsB = (char*)smem4;
    const int row0 = blockIdx.x * BM;
    const int tid = threadIdx.x;
    const int w = tid >> 6, l = tid & 63;

    // stage: 16 chunks of 2KB = (2 tiles x 8 slices); each chunk: [64 rows][32B],
    // content[r][sub] = global[r][sub ^ S(r)], S(r) = ((r>>2)&1)<<4
#pragma unroll
    for (int j = 0; j < 8; ++j) {
        int u = w * 8 + j;
        int chunk = u >> 1, halfc = u & 1;
        int tile = chunk >> 3, f = chunk & 7;
        int pos = halfc * 1024 + l * 16;
        int r = pos >> 5, sub = pos & 31;
        int S = ((r >> 2) & 1) << 4;
        const unsigned short* srcbase = (tile == 0 ? aggs : hs) + (size_t)f * SLICE_SHORTS;
        if (row0 + r < NN) {
            load_g2l_16(srcbase + (size_t)(row0 + r) * 16 + ((sub ^ S) >> 1),
                        ldsB + tile * 16384 + f * 2048 + pos);
        }
    }
    __syncthreads();

    const int wr = w & 1, wc = w >> 1;
    const int lrow = l & 15, lg = l >> 4;

    f32x4 acc[2][4];
#pragma unroll
    for (int m = 0; m < 2; ++m)
#pragma unroll
        for (int n = 0; n < 4; ++n) acc[m][n] = (f32x4){0.f, 0.f, 0.f, 0.f};

    float bv[4];
#pragma unroll
    for (int n = 0; n < 4; ++n) bv[n] = bias[wc * 64 + n * 16 + lrow];

#pragma unroll
    for (int kb = 0; kb < 4; ++kb) {
        const int kbyte = kb * 64 + lg * 16;
        const int f = kbyte >> 5, sub = kbyte & 31;
        bf16x8 aA[2], aH[2];
#pragma unroll
        for (int m = 0; m < 2; ++m) {
            int r = wr * 32 + m * 16 + lrow;
            int off = f * 2048 + r * 32 + (sub ^ (((r >> 2) & 1) << 4));
            aA[m] = *reinterpret_cast<const bf16x8*>(ldsB + off);
            aH[m] = *reinterpret_cast<const bf16x8*>(ldsB + 16384 + off);
        }
        bf16x8 bL[4], bR[4];
#pragma unroll
        for (int n = 0; n < 4; ++n) {
            size_t woff = ((size_t)(wc * 64 + n * 16 + lrow) << 7) + kb * 32 + lg * 8;
            bL[n] = *reinterpret_cast<const bf16x8*>(WlT + woff);
            bR[n] = *reinterpret_cast<const bf16x8*>(WrT + woff);
        }
#pragma unroll
        for (int m = 0; m < 2; ++m)
#pragma unroll
            for (int n = 0; n < 4; ++n) {
                acc[m][n] = __builtin_amdgcn_mfma_f32_16x16x32_bf16(aA[m], bL[n], acc[m][n], 0, 0, 0);
                acc[m][n] = __builtin_amdgcn_mfma_f32_16x16x32_bf16(aH[m], bR[n], acc[m][n], 0, 0, 0);
            }
    }

    // epilogue: bias+relu into fp32 LDS tile
    __syncthreads();
    float* otile = (float*)smem4;
#pragma unroll
    for (int m = 0; m < 2; ++m) {
        int rb = wr * 32 + m * 16 + lg * 4;
#pragma unroll
        for (int n = 0; n < 4; ++n) {
            int c = wc * 64 + n * 16 + lrow;
#pragma unroll
            for (int j = 0; j < 4; ++j)
                otile[(rb + j) * DD + c] = fmaxf(acc[m][n][j] + bv[n], 0.0f);
        }
    }
    __syncthreads();
    // fp32 out, coalesced
    const f32x4* t4 = (const f32x4*)smem4;
#pragma unroll
    for (int it = 0; it < 8; ++it) {
        int idx = it * 256 + tid;        // float4 units in 64x128 tile
        int r = idx >> 5;
        int gr = row0 + r;
        if (gr < NN)
            __builtin_nontemporal_store(t4[idx], (f32x4*)out + (size_t)gr * 32 + (idx & 31));
    }
    // bf16 h_next, slice-major
    if (hbn) {
#pragma unroll
        for (int it = 0; it < 4; ++it) {
            int u = it * 256 + tid;      // 8f x 64r x 2half
            int f = u >> 7, rem = u & 127;
            int r = rem >> 1, half = rem & 1;
            int n = row0 + r;
            if (n < NN) {
                const float* src = otile + r * DD + f * 16 + half * 8;
                uint4 pk;
                pk.x = packbf(src[0], src[1]);
                pk.y = packbf(src[2], src[3]);
                pk.z = packbf(src[4], src[5]);
                pk.w = packbf(src[6], src[7]);
                *reinterpret_cast<uint4*>(hbn + (size_t)f * SLICE_SHORTS + (size_t)n * 16 + half * 8) = pk;
            }
        }
    }
}

extern "C" void kernel_launch(void* const* d_in, const int* in_sizes, int n_in,
                              void* d_out, int out_size, void* d_ws, size_t ws_size,
                              hipStream_t stream) {
    const float* x = (const float*)d_in[0];
    const int* ei = (const int*)d_in[1];
    const int* row = ei;        // dst
    const int* col = ei + NE;   // src
    const float* Wl[3] = {(const float*)d_in[2], (const float*)d_in[5], (const float*)d_in[8]};
    const float* Wr[3] = {(const float*)d_in[3], (const float*)d_in[6], (const float*)d_in[9]};
    const float* bb[3] = {(const float*)d_in[4], (const float*)d_in[7], (const float*)d_in[10]};
    float* out = (float*)d_out;

    char* ws = (char*)d_ws;
    auto carve = [&](size_t bytes) {
        char* p = ws;
        ws += (bytes + 255) & ~(size_t)255;
        return p;
    };
    unsigned short* buf0 = (unsigned short*)carve((size_t)NN * DD * 2);  // sliced x / h2
    unsigned short* buf1 = (unsigned short*)carve((size_t)NN * DD * 2);  // sliced h1
    unsigned short* aggs = (unsigned short*)carve((size_t)NN * DD * 2);  // sliced agg
    unsigned short* wtall = (unsigned short*)carve((size_t)6 * DD * DD * 2);
    int* gcnt    = (int*)carve((size_t)2 * NBUCK * sizeof(int));  // gcnt + gcursor
    int* gcursor = gcnt + NBUCK;
    int* gbase   = (int*)carve((size_t)(NBUCK + 1) * sizeof(int));
    int* offs    = (int*)carve((size_t)(NN + 1) * sizeof(int));
    uint2* ebuf  = (uint2*)carve((size_t)NE * sizeof(uint2));     // 12.8 MB
    int* csr_col = (int*)carve((size_t)NE * sizeof(int));         // 6.4 MB

    hipMemsetAsync(gcnt, 0, (size_t)2 * NBUCK * sizeof(int), stream);

    const int ngrid = (NN + BM - 1) / BM;   // 1563
    conv_x_sliced<<<ngrid, 256, 0, stream>>>(x, buf0);
    prep_wh<<<CVW_BLK + NBLK_PART, 256, 0, stream>>>(
        Wl[0], Wr[0], Wl[1], Wr[1], Wl[2], Wr[2], wtall, row, gcnt);
    bucket_scan<<<1, 512, 0, stream>>>(gcnt, gbase);
    bucket_scatter<<<NBLK_PART, 256, 0, stream>>>(row, col, gbase, gcursor, ebuf);
    csr_build<<<NBUCK, 256, 0, stream>>>(ebuf, gbase, offs, csr_col);

    unsigned short* hin = buf0;
    unsigned short* hout = buf1;
    for (int lyr = 0; lyr < 3; ++lyr) {
        float* o = out + (size_t)lyr * NN * DD;
        agg_sliced<<<AGG_GRID, 512, 0, stream>>>(hin, offs, csr_col, aggs);
        gemm_sliced<<<ngrid, 256, 0, stream>>>(
            aggs, hin, wtall + (size_t)2 * lyr * DD * DD, wtall + (size_t)(2 * lyr + 1) * DD * DD,
            bb[lyr], o, (lyr < 2) ? hout : (unsigned short*)nullptr);
        unsigned short* t = hin; hin = hout; hout = t;
    }
}

// Round 7
// 318.881 us; speedup vs baseline: 1.5078x; 1.5078x over previous
//
#include <hip/hip_runtime.h>

#define NN 100000
#define NE 1600000
#define DD 128
#define BM 64
#define NPB 256                   // nodes per bucket
#define NBUCK 391                 // ceil(NN / NPB)
#define ECHUNK 8192
#define NBLK_PART 196             // ceil(NE / ECHUNK)
#define CAP 8192                  // LDS staging capacity (mean bucket = 4096 edges)
#define CVX_BLK 800
#define CVW_BLK 384

typedef __attribute__((ext_vector_type(2))) float f32x2;
typedef __attribute__((ext_vector_type(4))) float f32x4;
typedef __attribute__((ext_vector_type(8))) short bf16x8;

__device__ inline unsigned short f2bf(float f) {
    unsigned int x = __builtin_bit_cast(unsigned int, f);
    unsigned int r = x + 0x7fffu + ((x >> 16) & 1u);
    return (unsigned short)(r >> 16);
}
__device__ inline unsigned int packbf(float a, float b) {
    return (unsigned int)f2bf(a) | ((unsigned int)f2bf(b) << 16);
}
// fp8 e4m3 pack/unpack via gfx950 HW converts (codec is self-consistent)
__device__ inline unsigned int pk_fp8x4(float a, float b, float c, float d) {
    int v = 0;
    v = __builtin_amdgcn_cvt_pk_fp8_f32(a, b, v, false);
    v = __builtin_amdgcn_cvt_pk_fp8_f32(c, d, v, true);
    return (unsigned int)v;
}
__device__ inline f32x2 upk_fp8_lo(unsigned int v) {
    return __builtin_amdgcn_cvt_pk_f32_fp8((int)v, false);
}
__device__ inline f32x2 upk_fp8_hi(unsigned int v) {
    return __builtin_amdgcn_cvt_pk_f32_fp8((int)v, true);
}

__device__ inline void load_g2l_16(const void* gsrc, void* ldst) {
    __builtin_amdgcn_global_load_lds(
        (const __attribute__((address_space(1))) void*)(uintptr_t)gsrc,
        (__attribute__((address_space(3))) void*)(uintptr_t)ldst,
        16, 0, 0);
}

// ---------------- fused prep: conv_x (bf16 + fp8) + conv_w + bucket_hist ----------------

__global__ __launch_bounds__(256) void prep_kernel(
    const float* __restrict__ x, unsigned short* __restrict__ xb,
    unsigned int* __restrict__ xf8,
    const float* __restrict__ w0, const float* __restrict__ w1,
    const float* __restrict__ w2, const float* __restrict__ w3,
    const float* __restrict__ w4, const float* __restrict__ w5,
    unsigned short* __restrict__ wtall,
    const int* __restrict__ row, int* __restrict__ gcnt) {
    __shared__ int cnt[NBUCK];
    const int b = blockIdx.x;
    if (b < CVX_BLK) {
        int i = b * 256 + threadIdx.x;
        const int n4 = NN * DD / 4;
        for (; i < n4; i += CVX_BLK * 256) {
            float4 v = reinterpret_cast<const float4*>(x)[i];
            ushort4 o;
            o.x = f2bf(v.x); o.y = f2bf(v.y); o.z = f2bf(v.z); o.w = f2bf(v.w);
            reinterpret_cast<ushort4*>(xb)[i] = o;
            xf8[i] = pk_fp8x4(v.x, v.y, v.z, v.w);
        }
    } else if (b < CVX_BLK + CVW_BLK) {
        int t = (b - CVX_BLK) * 256 + threadIdx.x;   // 0 .. 6*16384-1
        int i = t >> 14;
        int r = t & 16383;
        const float* W = (i == 0) ? w0 : (i == 1) ? w1 : (i == 2) ? w2
                        : (i == 3) ? w3 : (i == 4) ? w4 : w5;
        int c = r >> 7, k = r & 127;
        wtall[t] = f2bf(W[k * DD + c]);
    } else {
        for (int i = threadIdx.x; i < NBUCK; i += 256) cnt[i] = 0;
        __syncthreads();
        int base = (b - CVX_BLK - CVW_BLK) * ECHUNK;
        int end = base + ECHUNK; if (end > NE) end = NE;
        for (int i = base + threadIdx.x; i < end; i += 256)
            atomicAdd(&cnt[row[i] >> 8], 1);
        __syncthreads();
        for (int i = threadIdx.x; i < NBUCK; i += 256) {
            int c = cnt[i];
            if (c) atomicAdd(&gcnt[i], c);
        }
    }
}

// ---------------- bucketed CSR build ----------------

__global__ __launch_bounds__(512) void bucket_scan(const int* __restrict__ gcnt,
                                                   int* __restrict__ gbase) {
    __shared__ int sm[512];
    int t = threadIdx.x;
    sm[t] = (t < NBUCK) ? gcnt[t] : 0;
    __syncthreads();
    for (int off = 1; off < 512; off <<= 1) {
        int add = (t >= off) ? sm[t - off] : 0;
        __syncthreads();
        sm[t] += add;
        __syncthreads();
    }
    if (t < NBUCK) gbase[t + 1] = sm[t];
    if (t == 0) gbase[0] = 0;
}

__global__ __launch_bounds__(256) void bucket_scatter(const int* __restrict__ row,
                                                      const int* __restrict__ col,
                                                      const int* __restrict__ gbase,
                                                      int* __restrict__ gcursor,
                                                      uint2* __restrict__ ebuf) {
    __shared__ int cnt[NBUCK];
    __shared__ int base[NBUCK];
    for (int i = threadIdx.x; i < NBUCK; i += 256) cnt[i] = 0;
    __syncthreads();
    int cbase = blockIdx.x * ECHUNK;
    int cend = cbase + ECHUNK; if (cend > NE) cend = NE;
    for (int i = cbase + threadIdx.x; i < cend; i += 256)
        atomicAdd(&cnt[row[i] >> 8], 1);
    __syncthreads();
    for (int i = threadIdx.x; i < NBUCK; i += 256) {
        int c = cnt[i];
        cnt[i] = 0;
        base[i] = c ? (gbase[i] + atomicAdd(&gcursor[i], c)) : 0;
    }
    __syncthreads();
    for (int i = cbase + threadIdx.x; i < cend; i += 256) {
        int r = row[i], c = col[i];
        int b = r >> 8;
        int k = atomicAdd(&cnt[b], 1);
        ebuf[base[b] + k] = uint2{(unsigned)r, (unsigned)c};
    }
}

__global__ __launch_bounds__(256) void csr_build(const uint2* __restrict__ ebuf,
                                                 const int* __restrict__ gbase,
                                                 int* __restrict__ offs,
                                                 int* __restrict__ csr_col) {
    __shared__ int dcnt[NPB];
    __shared__ int doff[NPB];
    __shared__ int sm[NPB];
    __shared__ int stage[CAP];
    const int b = blockIdx.x;
    const int es = gbase[b], ee = gbase[b + 1];
    const int m = ee - es;
    const int t = threadIdx.x;
    const int nbase = b * NPB;

    dcnt[t] = 0;
    __syncthreads();
    for (int i = es + t; i < ee; i += 256) {
        int ln = (int)ebuf[i].x - nbase;
        atomicAdd(&dcnt[ln], 1);
    }
    __syncthreads();
    sm[t] = dcnt[t];
    __syncthreads();
    for (int off = 1; off < 256; off <<= 1) {
        int add = (t >= off) ? sm[t - off] : 0;
        __syncthreads();
        sm[t] += add;
        __syncthreads();
    }
    doff[t] = sm[t] - dcnt[t];
    int node = nbase + t;
    if (node < NN) offs[node + 1] = es + sm[t];
    if (b == 0 && t == 0) offs[0] = 0;
    dcnt[t] = 0;
    __syncthreads();

    if (m <= CAP) {
        for (int i = es + t; i < ee; i += 256) {
            uint2 e = ebuf[i];
            int ln = (int)e.x - nbase;
            int k = atomicAdd(&dcnt[ln], 1);
            stage[doff[ln] + k] = (int)e.y;
        }
        __syncthreads();
        for (int i = t; i < m; i += 256) csr_col[es + i] = stage[i];
    } else {
        for (int i = es + t; i < ee; i += 256) {
            uint2 e = ebuf[i];
            int ln = (int)e.x - nbase;
            int k = atomicAdd(&dcnt[ln], 1);
            csr_col[es + doff[ln] + k] = (int)e.y;
        }
    }
}

// ---------------- fused layer: fp8 gather-aggregate + dual GEMM + epilogue ----------------

// per 64-row tile: gather-mean fp8 neighbors into swizzled bf16 A LDS tile,
// stage bf16 H via global_load_lds, MFMA relu(A@Wl + H@Wr + b), stream out via LDS.
__global__ __launch_bounds__(256) void fused_layer(
    const unsigned short* __restrict__ hb,           // bf16 h (self term)
    const unsigned int* __restrict__ f8,             // fp8 h (gather table), dword-viewed
    const int* __restrict__ offs, const int* __restrict__ csr_col,
    const unsigned short* __restrict__ WlT, const unsigned short* __restrict__ WrT,
    const float* __restrict__ bias, float* __restrict__ out,
    unsigned short* __restrict__ hbn, unsigned int* __restrict__ f8n) {
    __shared__ uint4 smem4[2048];            // 32KB: A(16KB) + H(16KB), reused as fp32 out tile
    char* AldsB = (char*)smem4;
    char* HldsB = AldsB + 16384;
    const int row0 = blockIdx.x * BM;
    const int tid = threadIdx.x;
    const int w = tid >> 6, l = tid & 63;

    // 1) issue H staging: 16KB, each wave a 4KB span
    const char* Hsrc = (const char*)(hb + (size_t)row0 * DD);
#pragma unroll
    for (int j = 0; j < 4; ++j) {
        int base = w * 4096 + j * 1024;
        int doff = base + l * 16;
        int soff = doff ^ (((doff >> 8) & 7) << 4);   // inverse swizzle on source
        if (row0 + (doff >> 8) < NN) load_g2l_16(Hsrc + soff, HldsB + base);
    }

    // 2) fp8 gather-aggregate A into LDS (bf16, swizzled), 16 lanes per node,
    //    8 B (8 dims) per lane -> 2 full 64B lines per neighbor row
    const int g16 = tid >> 4, lane = tid & 15;
    for (int i = 0; i < 4; ++i) {
        const int rloc = g16 * 4 + i;
        const int node = row0 + rloc;
        f32x2 a0 = {0.f, 0.f}, a1 = {0.f, 0.f}, a2 = {0.f, 0.f}, a3 = {0.f, 0.f};
        float inv = 0.0f;
        if (node < NN) {
            int s = offs[node], e = offs[node + 1];
            int p = s;
            for (; p + 8 <= e; p += 8) {
                uint2 v[8];
#pragma unroll
                for (int q = 0; q < 8; ++q) {
                    int c = csr_col[p + q];
                    v[q] = *reinterpret_cast<const uint2*>(f8 + (size_t)c * 32 + lane * 2);
                }
#pragma unroll
                for (int q = 0; q < 8; ++q) {
                    a0 += upk_fp8_lo(v[q].x);
                    a1 += upk_fp8_hi(v[q].x);
                    a2 += upk_fp8_lo(v[q].y);
                    a3 += upk_fp8_hi(v[q].y);
                }
            }
            for (; p < e; ++p) {
                int c = csr_col[p];
                uint2 v = *reinterpret_cast<const uint2*>(f8 + (size_t)c * 32 + lane * 2);
                a0 += upk_fp8_lo(v.x);
                a1 += upk_fp8_hi(v.x);
                a2 += upk_fp8_lo(v.y);
                a3 += upk_fp8_hi(v.y);
            }
            inv = (e > s) ? (1.0f / (float)(e - s)) : 0.0f;
        }
        uint4 o;
        o.x = packbf(a0[0] * inv, a0[1] * inv);
        o.y = packbf(a1[0] * inv, a1[1] * inv);
        o.z = packbf(a2[0] * inv, a2[1] * inv);
        o.w = packbf(a3[0] * inv, a3[1] * inv);
        int off = (rloc << 8) + ((lane * 16) ^ ((rloc & 7) << 4));
        *reinterpret_cast<uint4*>(AldsB + off) = o;
    }
    __syncthreads();

    // 3) MFMA
    const int wr = w & 1, wc = w >> 1;
    const int lrow = l & 15, lg = l >> 4;

    f32x4 acc[2][4];
#pragma unroll
    for (int m = 0; m < 2; ++m)
#pragma unroll
        for (int n = 0; n < 4; ++n) acc[m][n] = (f32x4){0.f, 0.f, 0.f, 0.f};

    float bv[4];
#pragma unroll
    for (int n = 0; n < 4; ++n) bv[n] = bias[wc * 64 + n * 16 + lrow];

#pragma unroll
    for (int kb = 0; kb < 4; ++kb) {
        const int kbyte = kb * 64 + lg * 16;
        bf16x8 aA[2], aH[2];
#pragma unroll
        for (int m = 0; m < 2; ++m) {
            int rloc = wr * 32 + m * 16 + lrow;
            int off = (rloc << 8) + kbyte;
            off ^= (rloc & 7) << 4;
            aA[m] = *reinterpret_cast<const bf16x8*>(AldsB + off);
            aH[m] = *reinterpret_cast<const bf16x8*>(HldsB + off);
        }
        bf16x8 bL[4], bR[4];
#pragma unroll
        for (int n = 0; n < 4; ++n) {
            size_t woff = ((size_t)(wc * 64 + n * 16 + lrow) << 7) + kb * 32 + lg * 8;
            bL[n] = *reinterpret_cast<const bf16x8*>(WlT + woff);
            bR[n] = *reinterpret_cast<const bf16x8*>(WrT + woff);
        }
#pragma unroll
        for (int m = 0; m < 2; ++m)
#pragma unroll
            for (int n = 0; n < 4; ++n) {
                acc[m][n] = __builtin_amdgcn_mfma_f32_16x16x32_bf16(aA[m], bL[n], acc[m][n], 0, 0, 0);
                acc[m][n] = __builtin_amdgcn_mfma_f32_16x16x32_bf16(aH[m], bR[n], acc[m][n], 0, 0, 0);
            }
    }

    // 4) epilogue: bias+relu into fp32 LDS tile, then stream coalesced
    __syncthreads();
    float* otile = (float*)smem4;
#pragma unroll
    for (int m = 0; m < 2; ++m) {
        int rb = wr * 32 + m * 16 + lg * 4;
#pragma unroll
        for (int n = 0; n < 4; ++n) {
            int c = wc * 64 + n * 16 + lrow;
#pragma unroll
            for (int j = 0; j < 4; ++j)
                otile[(rb + j) * DD + c] = fmaxf(acc[m][n][j] + bv[n], 0.0f);
        }
    }
    __syncthreads();
    const f32x4* t4 = (const f32x4*)smem4;
#pragma unroll
    for (int it = 0; it < 8; ++it) {
        int idx = it * 256 + tid;        // float4 index in 64x128 tile (2048 total)
        int r = idx >> 5;
        int gr = row0 + r;
        if (gr < NN) {
            f32x4 v = t4[idx];
            __builtin_nontemporal_store(v, (f32x4*)out + (size_t)gr * 32 + (idx & 31));
            if (hbn) {
                uint2 pk;
                pk.x = packbf(v[0], v[1]);
                pk.y = packbf(v[2], v[3]);
                *((uint2*)hbn + (size_t)gr * 32 + (idx & 31)) = pk;
                f8n[(size_t)gr * 32 + (idx & 31)] = pk_fp8x4(v[0], v[1], v[2], v[3]);
            }
        }
    }
}

extern "C" void kernel_launch(void* const* d_in, const int* in_sizes, int n_in,
                              void* d_out, int out_size, void* d_ws, size_t ws_size,
                              hipStream_t stream) {
    const float* x = (const float*)d_in[0];
    const int* ei = (const int*)d_in[1];
    const int* row = ei;        // dst
    const int* col = ei + NE;   // src
    const float* Wl[3] = {(const float*)d_in[2], (const float*)d_in[5], (const float*)d_in[8]};
    const float* Wr[3] = {(const float*)d_in[3], (const float*)d_in[6], (const float*)d_in[9]};
    const float* bb[3] = {(const float*)d_in[4], (const float*)d_in[7], (const float*)d_in[10]};
    float* out = (float*)d_out;

    char* ws = (char*)d_ws;
    auto carve = [&](size_t bytes) {
        char* p = ws;
        ws += (bytes + 255) & ~(size_t)255;
        return p;
    };
    unsigned short* buf0 = (unsigned short*)carve((size_t)NN * DD * 2);
    unsigned short* buf1 = (unsigned short*)carve((size_t)NN * DD * 2);
    unsigned int* f8a = (unsigned int*)carve((size_t)NN * DD);      // fp8 tables, 12.8 MB each
    unsigned int* f8b = (unsigned int*)carve((size_t)NN * DD);
    unsigned short* wtall = (unsigned short*)carve((size_t)6 * DD * DD * 2);
    int* gcnt    = (int*)carve((size_t)2 * NBUCK * sizeof(int));  // gcnt + gcursor
    int* gcursor = gcnt + NBUCK;
    int* gbase   = (int*)carve((size_t)(NBUCK + 1) * sizeof(int));
    int* offs    = (int*)carve((size_t)(NN + 1) * sizeof(int));
    uint2* ebuf  = (uint2*)carve((size_t)NE * sizeof(uint2));     // 12.8 MB
    int* csr_col = (int*)carve((size_t)NE * sizeof(int));         // 6.4 MB

    hipMemsetAsync(gcnt, 0, (size_t)2 * NBUCK * sizeof(int), stream);

    prep_kernel<<<CVX_BLK + CVW_BLK + NBLK_PART, 256, 0, stream>>>(
        x, buf0, f8a, Wl[0], Wr[0], Wl[1], Wr[1], Wl[2], Wr[2], wtall, row, gcnt);
    bucket_scan<<<1, 512, 0, stream>>>(gcnt, gbase);
    bucket_scatter<<<NBLK_PART, 256, 0, stream>>>(row, col, gbase, gcursor, ebuf);
    csr_build<<<NBUCK, 256, 0, stream>>>(ebuf, gbase, offs, csr_col);

    const int ngrid = (NN + BM - 1) / BM;   // 1563

    unsigned short* hin = buf0;
    unsigned short* hout = buf1;
    unsigned int* f8in = f8a;
    unsigned int* f8out = f8b;
    for (int lyr = 0; lyr < 3; ++lyr) {
        float* o = out + (size_t)lyr * NN * DD;
        fused_layer<<<ngrid, 256, 0, stream>>>(
            hin, f8in, offs, csr_col,
            wtall + (size_t)2 * lyr * DD * DD, wtall + (size_t)(2 * lyr + 1) * DD * DD,
            bb[lyr], o,
            (lyr < 2) ? hout : (unsigned short*)nullptr,
            (lyr < 2) ? f8out : (unsigned int*)nullptr);
        unsigned short* t = hin; hin = hout; hout = t;
        unsigned int* t8 = f8in; f8in = f8out; f8out = t8;
    }
}

// Round 8
// 314.195 us; speedup vs baseline: 1.5303x; 1.0149x over previous
//
#include <hip/hip_runtime.h>

#define NN 100000
#define NE 1600000
#define DD 128
#define BM 64
#define NPB 256                   // nodes per bucket
#define NBUCK 391                 // ceil(NN / NPB)
#define ECHUNK 8192
#define NBLK_PART 196             // ceil(NE / ECHUNK)
#define CAP 8192                  // LDS staging capacity (mean bucket = 4096 edges)
#define CVX_BLK 800
#define CVW_BLK 384

typedef __attribute__((ext_vector_type(2))) float f32x2;
typedef __attribute__((ext_vector_type(4))) float f32x4;
typedef __attribute__((ext_vector_type(8))) short bf16x8;

__device__ inline unsigned short f2bf(float f) {
    unsigned int x = __builtin_bit_cast(unsigned int, f);
    unsigned int r = x + 0x7fffu + ((x >> 16) & 1u);
    return (unsigned short)(r >> 16);
}
__device__ inline unsigned int packbf(float a, float b) {
    return (unsigned int)f2bf(a) | ((unsigned int)f2bf(b) << 16);
}
// fp8 e4m3 pack/unpack via gfx950 HW converts (codec is self-consistent)
__device__ inline unsigned int pk_fp8x4(float a, float b, float c, float d) {
    int v = 0;
    v = __builtin_amdgcn_cvt_pk_fp8_f32(a, b, v, false);
    v = __builtin_amdgcn_cvt_pk_fp8_f32(c, d, v, true);
    return (unsigned int)v;
}
__device__ inline f32x2 upk_fp8_lo(unsigned int v) {
    return __builtin_amdgcn_cvt_pk_f32_fp8((int)v, false);
}
__device__ inline f32x2 upk_fp8_hi(unsigned int v) {
    return __builtin_amdgcn_cvt_pk_f32_fp8((int)v, true);
}

// ---------------- fused prep: conv_x (bf16 + fp8) + conv_w + bucket_hist ----------------

__global__ __launch_bounds__(256) void prep_kernel(
    const float* __restrict__ x, unsigned short* __restrict__ xb,
    unsigned int* __restrict__ xf8,
    const float* __restrict__ w0, const float* __restrict__ w1,
    const float* __restrict__ w2, const float* __restrict__ w3,
    const float* __restrict__ w4, const float* __restrict__ w5,
    unsigned short* __restrict__ wtall,
    const int* __restrict__ row, int* __restrict__ gcnt) {
    __shared__ int cnt[NBUCK];
    const int b = blockIdx.x;
    if (b < CVX_BLK) {
        int i = b * 256 + threadIdx.x;
        const int n4 = NN * DD / 4;
        for (; i < n4; i += CVX_BLK * 256) {
            float4 v = reinterpret_cast<const float4*>(x)[i];
            ushort4 o;
            o.x = f2bf(v.x); o.y = f2bf(v.y); o.z = f2bf(v.z); o.w = f2bf(v.w);
            reinterpret_cast<ushort4*>(xb)[i] = o;
            xf8[i] = pk_fp8x4(v.x, v.y, v.z, v.w);
        }
    } else if (b < CVX_BLK + CVW_BLK) {
        int t = (b - CVX_BLK) * 256 + threadIdx.x;   // 0 .. 6*16384-1
        int i = t >> 14;
        int r = t & 16383;
        const float* W = (i == 0) ? w0 : (i == 1) ? w1 : (i == 2) ? w2
                        : (i == 3) ? w3 : (i == 4) ? w4 : w5;
        int c = r >> 7, k = r & 127;
        wtall[t] = f2bf(W[k * DD + c]);
    } else {
        for (int i = threadIdx.x; i < NBUCK; i += 256) cnt[i] = 0;
        __syncthreads();
        int base = (b - CVX_BLK - CVW_BLK) * ECHUNK;
        int end = base + ECHUNK; if (end > NE) end = NE;
        for (int i = base + threadIdx.x; i < end; i += 256)
            atomicAdd(&cnt[row[i] >> 8], 1);
        __syncthreads();
        for (int i = threadIdx.x; i < NBUCK; i += 256) {
            int c = cnt[i];
            if (c) atomicAdd(&gcnt[i], c);
        }
    }
}

// ---------------- bucketed CSR build ----------------

__global__ __launch_bounds__(512) void bucket_scan(const int* __restrict__ gcnt,
                                                   int* __restrict__ gbase) {
    __shared__ int sm[512];
    int t = threadIdx.x;
    sm[t] = (t < NBUCK) ? gcnt[t] : 0;
    __syncthreads();
    for (int off = 1; off < 512; off <<= 1) {
        int add = (t >= off) ? sm[t - off] : 0;
        __syncthreads();
        sm[t] += add;
        __syncthreads();
    }
    if (t < NBUCK) gbase[t + 1] = sm[t];
    if (t == 0) gbase[0] = 0;
}

// edges packed as (col<<8)|(row&255): row-in-bucket fits 8 bits, col fits 17
__global__ __launch_bounds__(256) void bucket_scatter(const int* __restrict__ row,
                                                      const int* __restrict__ col,
                                                      const int* __restrict__ gbase,
                                                      int* __restrict__ gcursor,
                                                      unsigned int* __restrict__ ebuf) {
    __shared__ int cnt[NBUCK];
    __shared__ int base[NBUCK];
    for (int i = threadIdx.x; i < NBUCK; i += 256) cnt[i] = 0;
    __syncthreads();
    int cbase = blockIdx.x * ECHUNK;
    int cend = cbase + ECHUNK; if (cend > NE) cend = NE;
    for (int i = cbase + threadIdx.x; i < cend; i += 256)
        atomicAdd(&cnt[row[i] >> 8], 1);
    __syncthreads();
    for (int i = threadIdx.x; i < NBUCK; i += 256) {
        int c = cnt[i];
        cnt[i] = 0;
        base[i] = c ? (gbase[i] + atomicAdd(&gcursor[i], c)) : 0;
    }
    __syncthreads();
    for (int i = cbase + threadIdx.x; i < cend; i += 256) {
        int r = row[i], c = col[i];
        int b = r >> 8;
        int k = atomicAdd(&cnt[b], 1);
        ebuf[base[b] + k] = ((unsigned)c << 8) | ((unsigned)r & 255u);
    }
}

__global__ __launch_bounds__(256) void csr_build(const unsigned int* __restrict__ ebuf,
                                                 const int* __restrict__ gbase,
                                                 int* __restrict__ offs,
                                                 int* __restrict__ csr_col) {
    __shared__ int dcnt[NPB];
    __shared__ int doff[NPB];
    __shared__ int sm[NPB];
    __shared__ int stage[CAP];
    const int b = blockIdx.x;
    const int es = gbase[b], ee = gbase[b + 1];
    const int m = ee - es;
    const int t = threadIdx.x;
    const int nbase = b * NPB;

    dcnt[t] = 0;
    __syncthreads();
    for (int i = es + t; i < ee; i += 256) {
        int ln = (int)(ebuf[i] & 255u);
        atomicAdd(&dcnt[ln], 1);
    }
    __syncthreads();
    sm[t] = dcnt[t];
    __syncthreads();
    for (int off = 1; off < 256; off <<= 1) {
        int add = (t >= off) ? sm[t - off] : 0;
        __syncthreads();
        sm[t] += add;
        __syncthreads();
    }
    doff[t] = sm[t] - dcnt[t];
    int node = nbase + t;
    if (node < NN) offs[node + 1] = es + sm[t];
    if (b == 0 && t == 0) offs[0] = 0;
    dcnt[t] = 0;
    __syncthreads();

    if (m <= CAP) {
        for (int i = es + t; i < ee; i += 256) {
            unsigned e = ebuf[i];
            int ln = (int)(e & 255u);
            int k = atomicAdd(&dcnt[ln], 1);
            stage[doff[ln] + k] = (int)(e >> 8);
        }
        __syncthreads();
        for (int i = t; i < m; i += 256) csr_col[es + i] = stage[i];
    } else {
        for (int i = es + t; i < ee; i += 256) {
            unsigned e = ebuf[i];
            int ln = (int)(e & 255u);
            int k = atomicAdd(&dcnt[ln], 1);
            csr_col[es + doff[ln] + k] = (int)(e >> 8);
        }
    }
}

// ---------------- fused layer: fp8 gather-aggregate + dual GEMM + epilogue ----------------

// per 64-row tile: gather-mean fp8 neighbors (8 lanes x 16B per node) into a
// swizzled bf16 A LDS tile (16KB); H fragments load directly from global into
// MFMA layout (issued first, hidden under gather); epilogue streams out via
// two 32-row passes through the same 16KB LDS.
__global__ __launch_bounds__(256) void fused_layer(
    const unsigned short* __restrict__ hb,           // bf16 h (self term)
    const unsigned int* __restrict__ f8,             // fp8 h (gather table), dword-viewed
    const int* __restrict__ offs, const int* __restrict__ csr_col,
    const unsigned short* __restrict__ WlT, const unsigned short* __restrict__ WrT,
    const float* __restrict__ bias, float* __restrict__ out,
    unsigned short* __restrict__ hbn, unsigned int* __restrict__ f8n) {
    __shared__ uint4 smem4[1024];            // 16KB: A tile, reused as fp32 half-out tile
    char* AldsB = (char*)smem4;
    const int row0 = blockIdx.x * BM;
    const int tid = threadIdx.x;
    const int w = tid >> 6, l = tid & 63;
    const int wr = w & 1, wc = w >> 1;
    const int lrow = l & 15, lg = l >> 4;

    // 1) H fragments straight from global in MFMA layout (latency hides under gather)
    bf16x8 aH[2][4];
#pragma unroll
    for (int m = 0; m < 2; ++m) {
        int gr = row0 + wr * 32 + m * 16 + lrow;
        if (gr >= NN) gr = NN - 1;
        const unsigned short* hrow = hb + (size_t)gr * DD;
#pragma unroll
        for (int kb = 0; kb < 4; ++kb)
            aH[m][kb] = *reinterpret_cast<const bf16x8*>(hrow + kb * 32 + lg * 8);
    }

    // 2) fp8 gather-aggregate: 8 lanes per node (16B/lane), 2 rows per group
    const int grp = tid >> 3, lane = tid & 7;
    const uint4* f84 = reinterpret_cast<const uint4*>(f8);
#pragma unroll
    for (int i = 0; i < 2; ++i) {
        const int rloc = grp * 2 + i;
        const int node = row0 + rloc;
        f32x2 a[8];
#pragma unroll
        for (int k = 0; k < 8; ++k) a[k] = (f32x2){0.f, 0.f};
        float inv = 0.0f;
        if (node < NN) {
            int s = offs[node], e = offs[node + 1];
            int p = s;
            for (; p + 8 <= e; p += 8) {
                uint4 v[8];
#pragma unroll
                for (int q = 0; q < 8; ++q)
                    v[q] = f84[(size_t)csr_col[p + q] * 8 + lane];
#pragma unroll
                for (int q = 0; q < 8; ++q) {
                    a[0] += upk_fp8_lo(v[q].x); a[1] += upk_fp8_hi(v[q].x);
                    a[2] += upk_fp8_lo(v[q].y); a[3] += upk_fp8_hi(v[q].y);
                    a[4] += upk_fp8_lo(v[q].z); a[5] += upk_fp8_hi(v[q].z);
                    a[6] += upk_fp8_lo(v[q].w); a[7] += upk_fp8_hi(v[q].w);
                }
            }
            for (; p < e; ++p) {
                uint4 v = f84[(size_t)csr_col[p] * 8 + lane];
                a[0] += upk_fp8_lo(v.x); a[1] += upk_fp8_hi(v.x);
                a[2] += upk_fp8_lo(v.y); a[3] += upk_fp8_hi(v.y);
                a[4] += upk_fp8_lo(v.z); a[5] += upk_fp8_hi(v.z);
                a[6] += upk_fp8_lo(v.w); a[7] += upk_fp8_hi(v.w);
            }
            inv = (e > s) ? (1.0f / (float)(e - s)) : 0.0f;
        }
        uint4 o0, o1;
        o0.x = packbf(a[0][0] * inv, a[0][1] * inv);
        o0.y = packbf(a[1][0] * inv, a[1][1] * inv);
        o0.z = packbf(a[2][0] * inv, a[2][1] * inv);
        o0.w = packbf(a[3][0] * inv, a[3][1] * inv);
        o1.x = packbf(a[4][0] * inv, a[4][1] * inv);
        o1.y = packbf(a[5][0] * inv, a[5][1] * inv);
        o1.z = packbf(a[6][0] * inv, a[6][1] * inv);
        o1.w = packbf(a[7][0] * inv, a[7][1] * inv);
        const int sw = (rloc & 7) << 4;
        const int rbase = rloc << 8;
        *reinterpret_cast<uint4*>(AldsB + rbase + ((lane * 32) ^ sw)) = o0;
        *reinterpret_cast<uint4*>(AldsB + rbase + ((lane * 32 + 16) ^ sw)) = o1;
    }
    __syncthreads();

    // 3) MFMA: acc = A@Wl + H@Wr
    f32x4 acc[2][4];
#pragma unroll
    for (int m = 0; m < 2; ++m)
#pragma unroll
        for (int n = 0; n < 4; ++n) acc[m][n] = (f32x4){0.f, 0.f, 0.f, 0.f};

    float bv[4];
#pragma unroll
    for (int n = 0; n < 4; ++n) bv[n] = bias[wc * 64 + n * 16 + lrow];

#pragma unroll
    for (int kb = 0; kb < 4; ++kb) {
        const int kbyte = kb * 64 + lg * 16;
        bf16x8 aA[2];
#pragma unroll
        for (int m = 0; m < 2; ++m) {
            int rloc = wr * 32 + m * 16 + lrow;
            int off = (rloc << 8) + kbyte;
            off ^= (rloc & 7) << 4;
            aA[m] = *reinterpret_cast<const bf16x8*>(AldsB + off);
        }
        bf16x8 bL[4], bR[4];
#pragma unroll
        for (int n = 0; n < 4; ++n) {
            size_t woff = ((size_t)(wc * 64 + n * 16 + lrow) << 7) + kb * 32 + lg * 8;
            bL[n] = *reinterpret_cast<const bf16x8*>(WlT + woff);
            bR[n] = *reinterpret_cast<const bf16x8*>(WrT + woff);
        }
#pragma unroll
        for (int m = 0; m < 2; ++m)
#pragma unroll
            for (int n = 0; n < 4; ++n) {
                acc[m][n] = __builtin_amdgcn_mfma_f32_16x16x32_bf16(aA[m], bL[n], acc[m][n], 0, 0, 0);
                acc[m][n] = __builtin_amdgcn_mfma_f32_16x16x32_bf16(aH[m][kb], bR[n], acc[m][n], 0, 0, 0);
            }
    }

    // 4) epilogue: two 32-row passes through the 16KB LDS, coalesced streams
    __syncthreads();
    float* otile = (float*)smem4;
#pragma unroll
    for (int half = 0; half < 2; ++half) {
        if (wr == half) {
#pragma unroll
            for (int m = 0; m < 2; ++m) {
                int rb = m * 16 + lg * 4;
#pragma unroll
                for (int n = 0; n < 4; ++n) {
                    int c = wc * 64 + n * 16 + lrow;
#pragma unroll
                    for (int j = 0; j < 4; ++j)
                        otile[(rb + j) * DD + c] = fmaxf(acc[m][n][j] + bv[n], 0.0f);
                }
            }
        }
        __syncthreads();
        const f32x4* t4 = (const f32x4*)smem4;
#pragma unroll
        for (int it = 0; it < 4; ++it) {
            int idx = it * 256 + tid;        // 1024 f32x4 units in 32x128 tile
            int r = idx >> 5;
            int gr = row0 + half * 32 + r;
            if (gr < NN) {
                f32x4 v = t4[idx];
                __builtin_nontemporal_store(v, (f32x4*)out + (size_t)gr * 32 + (idx & 31));
                if (hbn) {
                    uint2 pk;
                    pk.x = packbf(v[0], v[1]);
                    pk.y = packbf(v[2], v[3]);
                    *((uint2*)hbn + (size_t)gr * 32 + (idx & 31)) = pk;
                    f8n[(size_t)gr * 32 + (idx & 31)] = pk_fp8x4(v[0], v[1], v[2], v[3]);
                }
            }
        }
        __syncthreads();
    }
}

extern "C" void kernel_launch(void* const* d_in, const int* in_sizes, int n_in,
                              void* d_out, int out_size, void* d_ws, size_t ws_size,
                              hipStream_t stream) {
    const float* x = (const float*)d_in[0];
    const int* ei = (const int*)d_in[1];
    const int* row = ei;        // dst
    const int* col = ei + NE;   // src
    const float* Wl[3] = {(const float*)d_in[2], (const float*)d_in[5], (const float*)d_in[8]};
    const float* Wr[3] = {(const float*)d_in[3], (const float*)d_in[6], (const float*)d_in[9]};
    const float* bb[3] = {(const float*)d_in[4], (const float*)d_in[7], (const float*)d_in[10]};
    float* out = (float*)d_out;

    char* ws = (char*)d_ws;
    auto carve = [&](size_t bytes) {
        char* p = ws;
        ws += (bytes + 255) & ~(size_t)255;
        return p;
    };
    unsigned short* buf0 = (unsigned short*)carve((size_t)NN * DD * 2);
    unsigned short* buf1 = (unsigned short*)carve((size_t)NN * DD * 2);
    unsigned int* f8a = (unsigned int*)carve((size_t)NN * DD);      // fp8 tables, 12.8 MB each
    unsigned int* f8b = (unsigned int*)carve((size_t)NN * DD);
    unsigned short* wtall = (unsigned short*)carve((size_t)6 * DD * DD * 2);
    int* gcnt    = (int*)carve((size_t)2 * NBUCK * sizeof(int));  // gcnt + gcursor
    int* gcursor = gcnt + NBUCK;
    int* gbase   = (int*)carve((size_t)(NBUCK + 1) * sizeof(int));
    int* offs    = (int*)carve((size_t)(NN + 1) * sizeof(int));
    unsigned int* ebuf = (unsigned int*)carve((size_t)NE * sizeof(unsigned int)); // 6.4 MB
    int* csr_col = (int*)carve((size_t)NE * sizeof(int));         // 6.4 MB

    hipMemsetAsync(gcnt, 0, (size_t)2 * NBUCK * sizeof(int), stream);

    prep_kernel<<<CVX_BLK + CVW_BLK + NBLK_PART, 256, 0, stream>>>(
        x, buf0, f8a, Wl[0], Wr[0], Wl[1], Wr[1], Wl[2], Wr[2], wtall, row, gcnt);
    bucket_scan<<<1, 512, 0, stream>>>(gcnt, gbase);
    bucket_scatter<<<NBLK_PART, 256, 0, stream>>>(row, col, gbase, gcursor, ebuf);
    csr_build<<<NBUCK, 256, 0, stream>>>(ebuf, gbase, offs, csr_col);

    const int ngrid = (NN + BM - 1) / BM;   // 1563

    unsigned short* hin = buf0;
    unsigned short* hout = buf1;
    unsigned int* f8in = f8a;
    unsigned int* f8out = f8b;
    for (int lyr = 0; lyr < 3; ++lyr) {
        float* o = out + (size_t)lyr * NN * DD;
        fused_layer<<<ngrid, 256, 0, stream>>>(
            hin, f8in, offs, csr_col,
            wtall + (size_t)2 * lyr * DD * DD, wtall + (size_t)(2 * lyr + 1) * DD * DD,
            bb[lyr], o,
            (lyr < 2) ? hout : (unsigned short*)nullptr,
            (lyr < 2) ? f8out : (unsigned int*)nullptr);
        unsigned short* t = hin; hin = hout; hout = t;
        unsigned int* t8 = f8in; f8in = f8out; f8out = t8;
    }
}